// Round 1
// baseline (2475.703 us; speedup 1.0000x reference)
//
#include <hip/hip_runtime.h>
#include <math.h>

typedef __bf16 bf16_t;
typedef __bf16 bf16x8 __attribute__((ext_vector_type(8)));
typedef float  floatx4 __attribute__((ext_vector_type(4)));

#define D_MODEL 2048
#define NH      8
#define DQK     128
#define DV      256
#define SEQ     2048
#define MROWS   4096        // B*S
#define QKVO_N  6144        // q(1024) | k(1024) | v(2048) | o_pre(2048)
#define FF      8192

// ---------------------------------------------------------------- utilities

__device__ __forceinline__ void glds16(const void* g, void* l) {
  __builtin_amdgcn_global_load_lds(
      (const __attribute__((address_space(1))) void*)g,
      (__attribute__((address_space(3))) void*)l, 16, 0, 0);
}

// ------------------------------------------------- transpose f32 -> bf16 ^T
// in: [K][N] f32 row-major; out: [N][K] bf16 row-major
__global__ __launch_bounds__(256) void transpose_bf16_kernel(
    const float* __restrict__ in, bf16_t* __restrict__ out, int K, int N) {
  __shared__ float tile[64][65];
  int n0 = blockIdx.x * 64, k0 = blockIdx.y * 64;
  int tx = threadIdx.x & 63, tg = threadIdx.x >> 6;
#pragma unroll
  for (int i = tg; i < 64; i += 4)
    tile[i][tx] = in[(size_t)(k0 + i) * N + n0 + tx];
  __syncthreads();
#pragma unroll
  for (int i = tg; i < 64; i += 4)
    out[(size_t)(n0 + i) * K + k0 + tx] = (bf16_t)tile[tx][i];
}

// --------------------------------------------- RMSNorm (+ fused gate dots)
template<bool GATES>
__global__ __launch_bounds__(256) void rmsnorm_kernel(
    const float* __restrict__ xin, const float* __restrict__ w,
    bf16_t* __restrict__ out,
    const float* __restrict__ w_ig, const float* __restrict__ b_ig,
    const float* __restrict__ w_fg, const float* __restrict__ b_fg,
    float* __restrict__ gate_pre) {
  int row = blockIdx.x, tid = threadIdx.x;
  int lane = tid & 63, wvi = tid >> 6;
  const float* xr = xin + (size_t)row * D_MODEL;
  floatx4 v0 = *(const floatx4*)&xr[tid * 8];
  floatx4 v1 = *(const floatx4*)&xr[tid * 8 + 4];
  float ss = 0.f;
#pragma unroll
  for (int e = 0; e < 4; ++e) ss += v0[e] * v0[e] + v1[e] * v1[e];
#pragma unroll
  for (int off = 32; off > 0; off >>= 1) ss += __shfl_down(ss, off, 64);
  __shared__ float red[4];
  if (lane == 0) red[wvi] = ss;
  __syncthreads();
  float scale = rsqrtf((red[0] + red[1] + red[2] + red[3]) * (1.0f / D_MODEL) + 1e-6f);
  floatx4 w0 = *(const floatx4*)&w[tid * 8];
  floatx4 w1 = *(const floatx4*)&w[tid * 8 + 4];
  float h[8];
#pragma unroll
  for (int e = 0; e < 4; ++e) { h[e] = v0[e] * w0[e] * scale; h[4 + e] = v1[e] * w1[e] * scale; }
  bf16x8 ob;
#pragma unroll
  for (int e = 0; e < 8; ++e) ob[e] = (bf16_t)h[e];
  *(bf16x8*)&out[(size_t)row * D_MODEL + tid * 8] = ob;
  if constexpr (GATES) {
    float pg[16];
#pragma unroll
    for (int j = 0; j < 16; ++j) pg[j] = 0.f;
    int c0 = tid * 8;
#pragma unroll
    for (int e = 0; e < 8; ++e) {
      const float* wi = w_ig + (size_t)(c0 + e) * NH;
      const float* wf = w_fg + (size_t)(c0 + e) * NH;
#pragma unroll
      for (int j = 0; j < 8; ++j) { pg[j] += h[e] * wi[j]; pg[8 + j] += h[e] * wf[j]; }
    }
#pragma unroll
    for (int j = 0; j < 16; ++j) {
#pragma unroll
      for (int off = 32; off > 0; off >>= 1) pg[j] += __shfl_down(pg[j], off, 64);
    }
    __shared__ float redg[4][16];
    if (lane == 0) {
#pragma unroll
      for (int j = 0; j < 16; ++j) redg[wvi][j] = pg[j];
    }
    __syncthreads();
    if (tid < 16) {
      float t = redg[0][tid] + redg[1][tid] + redg[2][tid] + redg[3][tid];
      float bias = (tid < 8) ? b_ig[tid] : b_fg[tid - 8];
      gate_pre[(size_t)row * 16 + tid] = 15.0f * tanhf((t + bias) * (1.0f / 15.0f));
    }
  }
}

// -------------------------------------------------------------- gate scan
// Per (b,h): logfg = logsigmoid(f), Fcum = cumsum, G = i - Fcum,
// m = Fcum + cummax(G), ft = Fcum - m = -cummax(G)
__global__ __launch_bounds__(64) void gate_scan_kernel(
    const float* __restrict__ gate_pre, float* __restrict__ ftb,
    float* __restrict__ Gb, float* __restrict__ mb) {
  int bh = blockIdx.x;          // 0..15
  int b = bh >> 3, h = bh & 7;
  int lane = threadIdx.x;       // 0..63
  const int CH = SEQ / 64;      // 32
  float lf[CH], iv[CH];
  float ls = 0.f;
#pragma unroll
  for (int c = 0; c < CH; ++c) {
    int s = lane * CH + c;
    const float* gp = &gate_pre[(size_t)(b * SEQ + s) * 16];
    float fg = gp[8 + h];
    iv[c] = gp[h];
    float v = fminf(fg, 0.f) - log1pf(expf(-fabsf(fg)));
    lf[c] = v; ls += v;
  }
  // inclusive prefix-sum of lane totals
  float xs = ls;
#pragma unroll
  for (int off = 1; off < 64; off <<= 1) {
    float y = __shfl_up(xs, off, 64);
    if (lane >= off) xs += y;
  }
  float F0 = xs - ls;   // exclusive prefix
  float Fc = F0, Gv[CH], Fcs[CH], lmax = -3.0e38f;
#pragma unroll
  for (int c = 0; c < CH; ++c) {
    Fc += lf[c]; Fcs[c] = Fc;
    float g = iv[c] - Fc; Gv[c] = g;
    lmax = fmaxf(lmax, g);
  }
  float mx = lmax;
#pragma unroll
  for (int off = 1; off < 64; off <<= 1) {
    float y = __shfl_up(mx, off, 64);
    if (lane >= off) mx = fmaxf(mx, y);
  }
  float prev = __shfl_up(mx, 1, 64);
  if (lane == 0) prev = -3.0e38f;
  float run = prev;
  size_t base = (size_t)bh * SEQ + lane * CH;
#pragma unroll
  for (int c = 0; c < CH; ++c) {
    run = fmaxf(run, Gv[c]);
    ftb[base + c] = -run;
    Gb[base + c]  = Gv[c];
    mb[base + c]  = Fcs[c] + run;
  }
}

// ------------------------------------------------------------- MFMA GEMM
// C[M,N] = A[M,K](bf16) * Bt[N,K](bf16)^T ; 128x128 tile, 4 waves, BK=32
// EPI: 0 = store bf16 to Cb; 1 = Cf = Xres + acc (f32);
//      2 = Cb = bf16(silu(Gb) * acc); 3 = Cf += acc
template<int EPI>
__global__ __launch_bounds__(256) void gemm_kernel(
    const bf16_t* __restrict__ A, const bf16_t* __restrict__ Bt,
    int N, int K,
    float* __restrict__ Cf, const float* __restrict__ Xres,
    bf16_t* __restrict__ Cb, const bf16_t* __restrict__ Gg) {
  __shared__ bf16_t sA[128 * 32];
  __shared__ bf16_t sB[128 * 32];
  int tid = threadIdx.x;
  int wv = tid >> 6, lane = tid & 63;
  int m0 = blockIdx.y * 128, n0 = blockIdx.x * 128;
  int lrow = lane >> 2, lseg = lane & 3;
  const bf16_t* gA = A + (size_t)(m0 + wv * 16 + lrow) * K + lseg * 8;
  const bf16_t* gB = Bt + (size_t)(n0 + wv * 16 + lrow) * K + lseg * 8;
  bf16_t* lA0 = &sA[(wv * 16) * 32];
  bf16_t* lA1 = &sA[(wv * 16 + 64) * 32];
  bf16_t* lB0 = &sB[(wv * 16) * 32];
  bf16_t* lB1 = &sB[(wv * 16 + 64) * 32];
  size_t skip = (size_t)64 * K;

  int wm = wv & 1, wn = wv >> 1;
  int r16 = lane & 15, q4 = lane >> 4;
  floatx4 acc[4][4];
#pragma unroll
  for (int i = 0; i < 4; ++i)
#pragma unroll
    for (int j = 0; j < 4; ++j) {
      acc[i][j][0] = 0.f; acc[i][j][1] = 0.f; acc[i][j][2] = 0.f; acc[i][j][3] = 0.f;
    }

  int niter = K >> 5;
  for (int kt = 0; kt < niter; ++kt) {
    const bf16_t* pA = gA + kt * 32;
    const bf16_t* pB = gB + kt * 32;
    glds16(pA, lA0);
    glds16(pA + skip, lA1);
    glds16(pB, lB0);
    glds16(pB + skip, lB1);
    __syncthreads();
    bf16x8 af[4], bfr[4];
#pragma unroll
    for (int i = 0; i < 4; ++i)
      af[i] = *(const bf16x8*)&sA[(wm * 64 + i * 16 + r16) * 32 + q4 * 8];
#pragma unroll
    for (int j = 0; j < 4; ++j)
      bfr[j] = *(const bf16x8*)&sB[(wn * 64 + j * 16 + r16) * 32 + q4 * 8];
#pragma unroll
    for (int i = 0; i < 4; ++i)
#pragma unroll
      for (int j = 0; j < 4; ++j)
        acc[i][j] = __builtin_amdgcn_mfma_f32_16x16x32_bf16(af[i], bfr[j], acc[i][j], 0, 0, 0);
    __syncthreads();
  }
  // epilogue: C/D layout col=lane&15, row=(lane>>4)*4+reg
#pragma unroll
  for (int i = 0; i < 4; ++i) {
#pragma unroll
    for (int r = 0; r < 4; ++r) {
      int grow = m0 + wm * 64 + i * 16 + q4 * 4 + r;
      size_t rb = (size_t)grow * N;
#pragma unroll
      for (int j = 0; j < 4; ++j) {
        int gcol = n0 + wn * 64 + j * 16 + r16;
        float v = acc[i][j][r];
        if constexpr (EPI == 0) {
          Cb[rb + gcol] = (bf16_t)v;
        } else if constexpr (EPI == 1) {
          Cf[rb + gcol] = Xres[rb + gcol] + v;
        } else if constexpr (EPI == 2) {
          float g = (float)Gg[rb + gcol];
          Cb[rb + gcol] = (bf16_t)((g / (1.f + expf(-g))) * v);
        } else {
          Cf[rb + gcol] += v;
        }
      }
    }
  }
}

// ------------------------------------------------------------- attention
// Precomputed m removes online-softmax: weight(t,s) = exp(ft[t]+G[s]) * qk / sqrt(dqk)
// Epilogue fuses n-normalization, per-head RMSNorm, sigmoid(o_pre) gate.
__global__ __launch_bounds__(256) void attn_kernel(
    const bf16_t* __restrict__ qkvo, const float* __restrict__ ftb,
    const float* __restrict__ Gb, const float* __restrict__ mb,
    const float* __restrict__ mh_w, bf16_t* __restrict__ h_out) {
  constexpr int TQ = 32, TS = 32, QS = 136; // padded lds stride for Q/K
  __shared__ bf16_t sQ[TQ * QS];
  __shared__ bf16_t sK[TS * QS];
  __shared__ bf16_t sV[TS * DV];
  __shared__ float sP[TQ * TS];
  __shared__ float sFT[TQ], sM[TQ], sG[TS];
  __shared__ float sRed[TQ * 16];
  __shared__ float sInvN[TQ], sScale[TQ];
  int p = blockIdx.x, bh = blockIdx.y;
  int b = bh >> 3, h = bh & 7;
  int tid = threadIdx.x;
  int ty = tid >> 4, tx = tid & 15;
  size_t bh_off = (size_t)bh * SEQ;
  const float isq = 0.08838834764831845f; // 1/sqrt(128)

  for (int half = 0; half < 2; ++half) {
    int tt = half ? (63 - p) : p;   // pair tt with 63-tt: uniform 65 s-tiles/block
    int t0 = tt * TQ;
    __syncthreads();
#pragma unroll
    for (int u = 0; u < 2; ++u) {
      int flat = (u * 256 + tid) * 8;
      int r = flat >> 7, c = flat & 127;
      *(bf16x8*)&sQ[r * QS + c] =
          *(const bf16x8*)&qkvo[(size_t)(b * SEQ + t0 + r) * QKVO_N + h * DQK + c];
    }
    if (tid < TQ) {
      sFT[tid] = ftb[bh_off + t0 + tid];
      sM[tid]  = mb[bh_off + t0 + tid];
    }
    float O[2][16];
#pragma unroll
    for (int i = 0; i < 2; ++i)
#pragma unroll
      for (int e = 0; e < 16; ++e) O[i][e] = 0.f;
    float rowsum[2] = {0.f, 0.f};
    int nst = tt + 1;
    for (int st = 0; st < nst; ++st) {
      int s0 = st * TS;
      __syncthreads();
#pragma unroll
      for (int u = 0; u < 2; ++u) {
        int flat = (u * 256 + tid) * 8;
        int r = flat >> 7, c = flat & 127;
        *(bf16x8*)&sK[r * QS + c] =
            *(const bf16x8*)&qkvo[(size_t)(b * SEQ + s0 + r) * QKVO_N + 1024 + h * DQK + c];
      }
#pragma unroll
      for (int u = 0; u < 4; ++u) {
        int flat = (u * 256 + tid) * 8;
        int r = flat >> 8, c = flat & 255;
        *(bf16x8*)&sV[flat] =
            *(const bf16x8*)&qkvo[(size_t)(b * SEQ + s0 + r) * QKVO_N + 2048 + h * DV + c];
      }
      if (tid < TS) sG[tid] = Gb[bh_off + s0 + tid];
      __syncthreads();
      float sc[2][2] = {{0.f, 0.f}, {0.f, 0.f}};
#pragma unroll
      for (int kk = 0; kk < DQK; kk += 8) {
        bf16x8 q0 = *(const bf16x8*)&sQ[(ty * 2 + 0) * QS + kk];
        bf16x8 q1 = *(const bf16x8*)&sQ[(ty * 2 + 1) * QS + kk];
        bf16x8 k0 = *(const bf16x8*)&sK[(tx * 2 + 0) * QS + kk];
        bf16x8 k1 = *(const bf16x8*)&sK[(tx * 2 + 1) * QS + kk];
#pragma unroll
        for (int e = 0; e < 8; ++e) {
          float a0 = (float)q0[e], a1 = (float)q1[e];
          float c0 = (float)k0[e], c1 = (float)k1[e];
          sc[0][0] += a0 * c0; sc[0][1] += a0 * c1;
          sc[1][0] += a1 * c0; sc[1][1] += a1 * c1;
        }
      }
#pragma unroll
      for (int i = 0; i < 2; ++i) {
        int tg = t0 + ty * 2 + i;
#pragma unroll
        for (int j = 0; j < 2; ++j) {
          int sg = s0 + tx * 2 + j;
          float wgt = 0.f;
          if (sg <= tg)
            wgt = expf(sFT[ty * 2 + i] + sG[tx * 2 + j]) * sc[i][j] * isq;
          rowsum[i] += wgt;
          sP[(ty * 2 + i) * TS + tx * 2 + j] = wgt;
        }
      }
      __syncthreads();
#pragma unroll
      for (int ss = 0; ss < TS; ss += 4) {
        floatx4 p0 = *(const floatx4*)&sP[(ty * 2 + 0) * TS + ss];
        floatx4 p1 = *(const floatx4*)&sP[(ty * 2 + 1) * TS + ss];
#pragma unroll
        for (int j = 0; j < 4; ++j) {
          bf16x8 va = *(const bf16x8*)&sV[(ss + j) * DV + tx * 16];
          bf16x8 vb = *(const bf16x8*)&sV[(ss + j) * DV + tx * 16 + 8];
          float a = p0[j], c = p1[j];
#pragma unroll
          for (int e = 0; e < 8; ++e) {
            float fva = (float)va[e], fvb = (float)vb[e];
            O[0][e] += a * fva; O[0][8 + e] += a * fvb;
            O[1][e] += c * fva; O[1][8 + e] += c * fvb;
          }
        }
      }
    }
    // -------- epilogue: n = max(|rowsum|, exp(-m)); per-head RMSNorm; o-gate
    __syncthreads();
    sRed[(ty * 2 + 0) * 16 + tx] = rowsum[0];
    sRed[(ty * 2 + 1) * 16 + tx] = rowsum[1];
    __syncthreads();
    if (tid < TQ) {
      float s = 0.f;
#pragma unroll
      for (int u = 0; u < 16; ++u) s += sRed[tid * 16 + u];
      sInvN[tid] = 1.0f / fmaxf(fabsf(s), expf(-sM[tid]));
    }
    __syncthreads();
    float msq[2] = {0.f, 0.f};
#pragma unroll
    for (int i = 0; i < 2; ++i) {
      float inv = sInvN[ty * 2 + i];
#pragma unroll
      for (int e = 0; e < 16; ++e) { O[i][e] *= inv; msq[i] += O[i][e] * O[i][e]; }
    }
    sRed[(ty * 2 + 0) * 16 + tx] = msq[0];
    sRed[(ty * 2 + 1) * 16 + tx] = msq[1];
    __syncthreads();
    if (tid < TQ) {
      float s = 0.f;
#pragma unroll
      for (int u = 0; u < 16; ++u) s += sRed[tid * 16 + u];
      sScale[tid] = rsqrtf(s * (1.0f / DV) + 1e-6f);
    }
    __syncthreads();
#pragma unroll
    for (int i = 0; i < 2; ++i) {
      size_t gr = (size_t)(b * SEQ + t0 + ty * 2 + i);
      float scl = sScale[ty * 2 + i];
      bf16x8 opa = *(const bf16x8*)&qkvo[gr * QKVO_N + 4096 + h * DV + tx * 16];
      bf16x8 opb = *(const bf16x8*)&qkvo[gr * QKVO_N + 4096 + h * DV + tx * 16 + 8];
      bf16x8 oa, ob;
#pragma unroll
      for (int e = 0; e < 8; ++e) {
        int gcol = h * DV + tx * 16 + e;
        float sig = 1.0f / (1.0f + expf(-(float)opa[e]));
        oa[e] = (bf16_t)(sig * O[i][e] * scl * mh_w[gcol]);
        sig = 1.0f / (1.0f + expf(-(float)opb[e]));
        ob[e] = (bf16_t)(sig * O[i][8 + e] * scl * mh_w[gcol + 8]);
      }
      *(bf16x8*)&h_out[gr * D_MODEL + h * DV + tx * 16] = oa;
      *(bf16x8*)&h_out[gr * D_MODEL + h * DV + tx * 16 + 8] = ob;
    }
  }
}

// ---------------------------------------------------------------- launcher

extern "C" void kernel_launch(void* const* d_in, const int* in_sizes, int n_in,
                              void* d_out, int out_size, void* d_ws, size_t ws_size,
                              hipStream_t stream) {
  const float* x      = (const float*)d_in[0];
  const float* n1w    = (const float*)d_in[1];
  const float* wq     = (const float*)d_in[2];
  const float* wk     = (const float*)d_in[3];
  const float* wvp    = (const float*)d_in[4];
  const float* w_ig   = (const float*)d_in[5];
  const float* b_ig   = (const float*)d_in[6];
  const float* w_fg   = (const float*)d_in[7];
  const float* b_fg   = (const float*)d_in[8];
  const float* w_og   = (const float*)d_in[9];
  const float* mh_w   = (const float*)d_in[10];
  const float* w_out  = (const float*)d_in[11];
  const float* n2w    = (const float*)d_in[12];
  const float* w_gate = (const float*)d_in[13];
  const float* w_up   = (const float*)d_in[14];
  const float* w_down = (const float*)d_in[15];
  float* out = (float*)d_out;
  (void)in_sizes; (void)n_in; (void)out_size; (void)ws_size;

  char* base = (char*)d_ws;
  size_t off = 0;
  auto alloc = [&](size_t bytes) -> void* {
    void* pp = base + off;
    off += (bytes + 255) & ~(size_t)255;
    return pp;
  };
  bf16_t* wT_qkvo = (bf16_t*)alloc((size_t)QKVO_N * 2048 * 2);
  bf16_t* wT_out  = (bf16_t*)alloc((size_t)2048 * 2048 * 2);
  bf16_t* wT_gate = (bf16_t*)alloc((size_t)FF * 2048 * 2);
  bf16_t* wT_up   = (bf16_t*)alloc((size_t)FF * 2048 * 2);
  bf16_t* wT_down = (bf16_t*)alloc((size_t)2048 * FF * 2);
  bf16_t* h_in    = (bf16_t*)alloc((size_t)MROWS * 2048 * 2);   // reused as h2
  float*  gate_pre= (float*)alloc((size_t)MROWS * 16 * 4);
  float*  ftb     = (float*)alloc((size_t)16 * SEQ * 4);
  float*  Gbuf    = (float*)alloc((size_t)16 * SEQ * 4);
  float*  mbuf    = (float*)alloc((size_t)16 * SEQ * 4);
  bf16_t* qkvo    = (bf16_t*)alloc((size_t)MROWS * QKVO_N * 2); // 48MB
  bf16_t* h_out   = (bf16_t*)alloc((size_t)MROWS * 2048 * 2);   // 16MB (right after qkvo)
  bf16_t* gbuf    = (bf16_t*)alloc((size_t)MROWS * FF * 2);
  bf16_t* tbuf    = qkvo;  // alias qkvo+h_out (64MB, both dead by then)

  dim3 blk(256);
  // weight transposes -> bf16 [N][K]
  transpose_bf16_kernel<<<dim3(16, 32), blk, 0, stream>>>(wq, wT_qkvo, 2048, 1024);
  transpose_bf16_kernel<<<dim3(16, 32), blk, 0, stream>>>(wk, wT_qkvo + (size_t)1024 * 2048, 2048, 1024);
  transpose_bf16_kernel<<<dim3(32, 32), blk, 0, stream>>>(wvp, wT_qkvo + (size_t)2048 * 2048, 2048, 2048);
  transpose_bf16_kernel<<<dim3(32, 32), blk, 0, stream>>>(w_og, wT_qkvo + (size_t)4096 * 2048, 2048, 2048);
  transpose_bf16_kernel<<<dim3(32, 32), blk, 0, stream>>>(w_out, wT_out, 2048, 2048);
  transpose_bf16_kernel<<<dim3(128, 32), blk, 0, stream>>>(w_gate, wT_gate, 2048, FF);
  transpose_bf16_kernel<<<dim3(128, 32), blk, 0, stream>>>(w_up, wT_up, 2048, FF);
  transpose_bf16_kernel<<<dim3(32, 128), blk, 0, stream>>>(w_down, wT_down, FF, 2048);

  rmsnorm_kernel<true><<<MROWS, blk, 0, stream>>>(x, n1w, h_in, w_ig, b_ig, w_fg, b_fg, gate_pre);
  gate_scan_kernel<<<16, 64, 0, stream>>>(gate_pre, ftb, Gbuf, mbuf);

  gemm_kernel<0><<<dim3(QKVO_N / 128, 32), blk, 0, stream>>>(
      h_in, wT_qkvo, QKVO_N, 2048, nullptr, nullptr, qkvo, nullptr);

  attn_kernel<<<dim3(32, 16), blk, 0, stream>>>(qkvo, ftb, Gbuf, mbuf, mh_w, h_out);

  gemm_kernel<1><<<dim3(16, 32), blk, 0, stream>>>(
      h_out, wT_out, 2048, 2048, out, x, nullptr, nullptr);

  rmsnorm_kernel<false><<<MROWS, blk, 0, stream>>>(out, n2w, h_in,
      nullptr, nullptr, nullptr, nullptr, nullptr);

  gemm_kernel<0><<<dim3(FF / 128, 32), blk, 0, stream>>>(
      h_in, wT_gate, FF, 2048, nullptr, nullptr, gbuf, nullptr);
  gemm_kernel<2><<<dim3(FF / 128, 32), blk, 0, stream>>>(
      h_in, wT_up, FF, 2048, nullptr, nullptr, tbuf, gbuf);
  gemm_kernel<3><<<dim3(16, 32), blk, 0, stream>>>(
      tbuf, wT_down, 2048, FF, out, nullptr, nullptr, nullptr);
}

// Round 2
// 1405.114 us; speedup vs baseline: 1.7619x; 1.7619x over previous
//
#include <hip/hip_runtime.h>
#include <math.h>

typedef __bf16 bf16_t;
typedef __bf16 bf16x8 __attribute__((ext_vector_type(8)));
typedef float  floatx4 __attribute__((ext_vector_type(4)));

#define D_MODEL 2048
#define NH      8
#define DQK     128
#define DV      256
#define SEQ     2048
#define MROWS   4096        // B*S
#define QKVO_N  6144        // q(1024) | k(1024) | v(2048) | o_pre(2048)
#define FF      8192

// ---------------------------------------------------------------- utilities

__device__ __forceinline__ void glds16(const void* g, void* l) {
  __builtin_amdgcn_global_load_lds(
      (const __attribute__((address_space(1))) void*)g,
      (__attribute__((address_space(3))) void*)l, 16, 0, 0);
}

// ------------------------------------------------- transpose f32 -> bf16 ^T
// in: [K][N] f32 row-major; out: [N][K] bf16 row-major
__global__ __launch_bounds__(256) void transpose_bf16_kernel(
    const float* __restrict__ in, bf16_t* __restrict__ out, int K, int N) {
  __shared__ float tile[64][65];
  int n0 = blockIdx.x * 64, k0 = blockIdx.y * 64;
  int tx = threadIdx.x & 63, tg = threadIdx.x >> 6;
#pragma unroll
  for (int i = tg; i < 64; i += 4)
    tile[i][tx] = in[(size_t)(k0 + i) * N + n0 + tx];
  __syncthreads();
#pragma unroll
  for (int i = tg; i < 64; i += 4)
    out[(size_t)(n0 + i) * K + k0 + tx] = (bf16_t)tile[tx][i];
}

// ------------------------------------------- transpose v (bf16) -> [dv][s]
// in: qkvo [bs][6144], v block at +2048 ; out: vt[bh][dv][s]
__global__ __launch_bounds__(256) void vtrans_kernel(
    const bf16_t* __restrict__ qkvo, bf16_t* __restrict__ vt) {
  __shared__ bf16_t tile[64 * 64];  // XOR-swizzled [d][s]
  int s0 = blockIdx.x * 64;         // 32
  int d0 = blockIdx.y * 64;         // 4
  int bh = blockIdx.z;              // 16
  int b = bh >> 3, h = bh & 7;
  int tid = threadIdx.x;
  int r = tid >> 3, c8 = tid & 7;
#pragma unroll
  for (int u = 0; u < 2; ++u) {
    int rr = r + u * 32;  // s index
    bf16x8 v = *(const bf16x8*)&qkvo[(size_t)(b * SEQ + s0 + rr) * QKVO_N +
                                     2048 + h * DV + d0 + c8 * 8];
#pragma unroll
    for (int e = 0; e < 8; ++e) {
      int d = c8 * 8 + e;
      tile[d * 64 + (rr ^ ((e ^ c8) * 8))] = v[e];
    }
  }
  __syncthreads();
#pragma unroll
  for (int u = 0; u < 2; ++u) {
    int rr = r + u * 32;  // d index
    int cc = (c8 ^ (rr & 7) ^ ((rr >> 3) & 7)) * 8;
    bf16x8 v = *(const bf16x8*)&tile[rr * 64 + cc];
    *(bf16x8*)&vt[((size_t)bh * DV + d0 + rr) * SEQ + s0 + c8 * 8] = v;
  }
}

// --------------------------------------------- RMSNorm (+ fused gate dots)
template<bool GATES>
__global__ __launch_bounds__(256) void rmsnorm_kernel(
    const float* __restrict__ xin, const float* __restrict__ w,
    bf16_t* __restrict__ out,
    const float* __restrict__ w_ig, const float* __restrict__ b_ig,
    const float* __restrict__ w_fg, const float* __restrict__ b_fg,
    float* __restrict__ gate_pre) {
  int row = blockIdx.x, tid = threadIdx.x;
  int lane = tid & 63, wvi = tid >> 6;
  const float* xr = xin + (size_t)row * D_MODEL;
  floatx4 v0 = *(const floatx4*)&xr[tid * 8];
  floatx4 v1 = *(const floatx4*)&xr[tid * 8 + 4];
  float ss = 0.f;
#pragma unroll
  for (int e = 0; e < 4; ++e) ss += v0[e] * v0[e] + v1[e] * v1[e];
#pragma unroll
  for (int off = 32; off > 0; off >>= 1) ss += __shfl_down(ss, off, 64);
  __shared__ float red[4];
  if (lane == 0) red[wvi] = ss;
  __syncthreads();
  float scale = rsqrtf((red[0] + red[1] + red[2] + red[3]) * (1.0f / D_MODEL) + 1e-6f);
  floatx4 w0 = *(const floatx4*)&w[tid * 8];
  floatx4 w1 = *(const floatx4*)&w[tid * 8 + 4];
  float h[8];
#pragma unroll
  for (int e = 0; e < 4; ++e) { h[e] = v0[e] * w0[e] * scale; h[4 + e] = v1[e] * w1[e] * scale; }
  bf16x8 ob;
#pragma unroll
  for (int e = 0; e < 8; ++e) ob[e] = (bf16_t)h[e];
  *(bf16x8*)&out[(size_t)row * D_MODEL + tid * 8] = ob;
  if constexpr (GATES) {
    float pg[16];
#pragma unroll
    for (int j = 0; j < 16; ++j) pg[j] = 0.f;
    int c0 = tid * 8;
#pragma unroll
    for (int e = 0; e < 8; ++e) {
      const float* wi = w_ig + (size_t)(c0 + e) * NH;
      const float* wf = w_fg + (size_t)(c0 + e) * NH;
#pragma unroll
      for (int j = 0; j < 8; ++j) { pg[j] += h[e] * wi[j]; pg[8 + j] += h[e] * wf[j]; }
    }
#pragma unroll
    for (int j = 0; j < 16; ++j) {
#pragma unroll
      for (int off = 32; off > 0; off >>= 1) pg[j] += __shfl_down(pg[j], off, 64);
    }
    __shared__ float redg[4][16];
    if (lane == 0) {
#pragma unroll
      for (int j = 0; j < 16; ++j) redg[wvi][j] = pg[j];
    }
    __syncthreads();
    if (tid < 16) {
      float t = redg[0][tid] + redg[1][tid] + redg[2][tid] + redg[3][tid];
      float bias = (tid < 8) ? b_ig[tid] : b_fg[tid - 8];
      gate_pre[(size_t)row * 16 + tid] = 15.0f * tanhf((t + bias) * (1.0f / 15.0f));
    }
  }
}

// -------------------------------------------------------------- gate scan
// Per (b,h): logfg = logsigmoid(f), Fcum = cumsum, G = i - Fcum,
// m = Fcum + cummax(G), ft = Fcum - m = -cummax(G)  (+ log(1/sqrt(dqk)) folded)
__global__ __launch_bounds__(64) void gate_scan_kernel(
    const float* __restrict__ gate_pre, float* __restrict__ ftb,
    float* __restrict__ Gb, float* __restrict__ mb) {
  int bh = blockIdx.x;          // 0..15
  int b = bh >> 3, h = bh & 7;
  int lane = threadIdx.x;       // 0..63
  const int CH = SEQ / 64;      // 32
  float lf[CH], iv[CH];
  float ls = 0.f;
#pragma unroll
  for (int c = 0; c < CH; ++c) {
    int s = lane * CH + c;
    const float* gp = &gate_pre[(size_t)(b * SEQ + s) * 16];
    float fg = gp[8 + h];
    iv[c] = gp[h];
    float v = fminf(fg, 0.f) - log1pf(expf(-fabsf(fg)));
    lf[c] = v; ls += v;
  }
  float xs = ls;
#pragma unroll
  for (int off = 1; off < 64; off <<= 1) {
    float y = __shfl_up(xs, off, 64);
    if (lane >= off) xs += y;
  }
  float F0 = xs - ls;   // exclusive prefix
  float Fc = F0, Gv[CH], Fcs[CH], lmax = -3.0e38f;
#pragma unroll
  for (int c = 0; c < CH; ++c) {
    Fc += lf[c]; Fcs[c] = Fc;
    float g = iv[c] - Fc; Gv[c] = g;
    lmax = fmaxf(lmax, g);
  }
  float mx = lmax;
#pragma unroll
  for (int off = 1; off < 64; off <<= 1) {
    float y = __shfl_up(mx, off, 64);
    if (lane >= off) mx = fmaxf(mx, y);
  }
  float prev = __shfl_up(mx, 1, 64);
  if (lane == 0) prev = -3.0e38f;
  float run = prev;
  size_t base = (size_t)bh * SEQ + lane * CH;
  const float LOG_ISQ = -2.42601515f;  // log(1/sqrt(128))
#pragma unroll
  for (int c = 0; c < CH; ++c) {
    run = fmaxf(run, Gv[c]);
    ftb[base + c] = -run + LOG_ISQ;
    Gb[base + c]  = Gv[c];
    mb[base + c]  = Fcs[c] + run;
  }
}

// ------------------------------------------------------------- MFMA GEMM
// C[M,N] = A[M,K](bf16) * Bt[N,K](bf16)^T ; 128x128 tile, 4 waves, BK=32
// EPI: 0 = store bf16 to Cb; 1 = Cf = Xres + acc (f32);
//      2 = Cb = bf16(silu(Gb) * acc); 3 = Cf += acc
template<int EPI>
__global__ __launch_bounds__(256) void gemm_kernel(
    const bf16_t* __restrict__ A, const bf16_t* __restrict__ Bt,
    int N, int K,
    float* __restrict__ Cf, const float* __restrict__ Xres,
    bf16_t* __restrict__ Cb, const bf16_t* __restrict__ Gg) {
  __shared__ bf16_t sA[128 * 32];
  __shared__ bf16_t sB[128 * 32];
  int tid = threadIdx.x;
  int wv = tid >> 6, lane = tid & 63;
  int m0 = blockIdx.y * 128, n0 = blockIdx.x * 128;
  int lrow = lane >> 2, lseg = lane & 3;
  const bf16_t* gA = A + (size_t)(m0 + wv * 16 + lrow) * K + lseg * 8;
  const bf16_t* gB = Bt + (size_t)(n0 + wv * 16 + lrow) * K + lseg * 8;
  bf16_t* lA0 = &sA[(wv * 16) * 32];
  bf16_t* lA1 = &sA[(wv * 16 + 64) * 32];
  bf16_t* lB0 = &sB[(wv * 16) * 32];
  bf16_t* lB1 = &sB[(wv * 16 + 64) * 32];
  size_t skip = (size_t)64 * K;

  int wm = wv & 1, wn = wv >> 1;
  int r16 = lane & 15, q4 = lane >> 4;
  floatx4 acc[4][4];
#pragma unroll
  for (int i = 0; i < 4; ++i)
#pragma unroll
    for (int j = 0; j < 4; ++j) {
      acc[i][j][0] = 0.f; acc[i][j][1] = 0.f; acc[i][j][2] = 0.f; acc[i][j][3] = 0.f;
    }

  int niter = K >> 5;
  for (int kt = 0; kt < niter; ++kt) {
    const bf16_t* pA = gA + kt * 32;
    const bf16_t* pB = gB + kt * 32;
    glds16(pA, lA0);
    glds16(pA + skip, lA1);
    glds16(pB, lB0);
    glds16(pB + skip, lB1);
    __syncthreads();
    bf16x8 af[4], bfr[4];
#pragma unroll
    for (int i = 0; i < 4; ++i)
      af[i] = *(const bf16x8*)&sA[(wm * 64 + i * 16 + r16) * 32 + q4 * 8];
#pragma unroll
    for (int j = 0; j < 4; ++j)
      bfr[j] = *(const bf16x8*)&sB[(wn * 64 + j * 16 + r16) * 32 + q4 * 8];
#pragma unroll
    for (int i = 0; i < 4; ++i)
#pragma unroll
      for (int j = 0; j < 4; ++j)
        acc[i][j] = __builtin_amdgcn_mfma_f32_16x16x32_bf16(af[i], bfr[j], acc[i][j], 0, 0, 0);
    __syncthreads();
  }
  // epilogue: C/D layout col=lane&15, row=(lane>>4)*4+reg
#pragma unroll
  for (int i = 0; i < 4; ++i) {
#pragma unroll
    for (int r = 0; r < 4; ++r) {
      int grow = m0 + wm * 64 + i * 16 + q4 * 4 + r;
      size_t rb = (size_t)grow * N;
#pragma unroll
      for (int j = 0; j < 4; ++j) {
        int gcol = n0 + wn * 64 + j * 16 + r16;
        float v = acc[i][j][r];
        if constexpr (EPI == 0) {
          Cb[rb + gcol] = (bf16_t)v;
        } else if constexpr (EPI == 1) {
          Cf[rb + gcol] = Xres[rb + gcol] + v;
        } else if constexpr (EPI == 2) {
          float g = (float)Gg[rb + gcol];
          Cb[rb + gcol] = (bf16_t)((g / (1.f + expf(-g))) * v);
        } else {
          Cf[rb + gcol] += v;
        }
      }
    }
  }
}

// ------------------------------------------------------------- attention
// MFMA flash loop. TQ=32 q-rows/block, TS=64 s-tile, 4 waves.
// Q A-frags in regs; K,V B-frags direct from global (16B/lane gathers).
// P (32x64) round-trips through LDS between QK^T (C-layout) and PV (A-layout).
// wv: mf=wv&1 (q-row half for QK), nh=wv>>1 (s-col half for QK); dv range wv*64 for PV.
__global__ __launch_bounds__(256) void attn_kernel(
    const bf16_t* __restrict__ qkvo, const bf16_t* __restrict__ vt,
    const float* __restrict__ ftb, const float* __restrict__ Gb,
    const float* __restrict__ mb, const float* __restrict__ mh_w,
    bf16_t* __restrict__ h_out) {
  constexpr int PS = 72;  // sP stride (16B-aligned rows)
  __shared__ bf16_t sP[32 * PS];
  __shared__ float sRS[32][2];
  __shared__ float sMS[32][4];
  __shared__ float sInvN[32];
  __shared__ float sSc[32];
  int p = blockIdx.x, bh = blockIdx.y;
  int b = bh >> 3, h = bh & 7;
  int tid = threadIdx.x;
  int wv = tid >> 6, lane = tid & 63;
  int r16 = lane & 15, q4 = lane >> 4;
  int mf = wv & 1, nh = wv >> 1;
  int dvb = wv * 64;
  size_t bh_off = (size_t)bh * SEQ;

  float mw[4];
#pragma unroll
  for (int nf = 0; nf < 4; ++nf) mw[nf] = mh_w[h * DV + dvb + nf * 16 + r16];

  for (int half = 0; half < 2; ++half) {
    int tt = half ? (63 - p) : p;
    int t0 = tt * 32;
    __syncthreads();
    // Q A-frags for the whole s-loop
    bf16x8 qf[4];
    {
      const bf16_t* qrow =
          qkvo + (size_t)(b * SEQ + t0 + mf * 16 + r16) * QKVO_N + h * DQK + q4 * 8;
#pragma unroll
      for (int kt = 0; kt < 4; ++kt) qf[kt] = *(const bf16x8*)(qrow + kt * 32);
    }
    float ft[4];
#pragma unroll
    for (int r = 0; r < 4; ++r) ft[r] = ftb[bh_off + t0 + mf * 16 + q4 * 4 + r];

    floatx4 Of[2][4];
#pragma unroll
    for (int i = 0; i < 2; ++i)
#pragma unroll
      for (int j = 0; j < 4; ++j) Of[i][j] = (floatx4){0.f, 0.f, 0.f, 0.f};
    float rs[4] = {0.f, 0.f, 0.f, 0.f};

    int nst = (tt >> 1) + 1;
    const bf16_t* kp =
        qkvo + (size_t)(b * SEQ + nh * 32 + r16) * QKVO_N + 1024 + h * DQK + q4 * 8;
    const bf16_t* vp = vt + ((size_t)bh * DV + dvb + r16) * SEQ + q4 * 8;
    for (int st = 0; st < nst; ++st) {
      int s0 = st * 64;
      // ---- QK^T
      floatx4 sc[2] = {{0.f, 0.f, 0.f, 0.f}, {0.f, 0.f, 0.f, 0.f}};
#pragma unroll
      for (int nf = 0; nf < 2; ++nf) {
        const bf16_t* kpn = kp + (size_t)(s0 + nf * 16) * QKVO_N;
#pragma unroll
        for (int kt = 0; kt < 4; ++kt) {
          bf16x8 kf = *(const bf16x8*)(kpn + kt * 32);
          sc[nf] = __builtin_amdgcn_mfma_f32_16x16x32_bf16(qf[kt], kf, sc[nf], 0, 0, 0);
        }
      }
      // ---- weights: w = exp(ft[t] + G[s]) * qk   (isq folded into ft)
      bool diag = (st == nst - 1);
#pragma unroll
      for (int nf = 0; nf < 2; ++nf) {
        int scol = s0 + nh * 32 + nf * 16 + r16;
        float g = Gb[bh_off + scol];
#pragma unroll
        for (int r = 0; r < 4; ++r) {
          int trow = t0 + mf * 16 + q4 * 4 + r;
          float w = __expf(ft[r] + g) * sc[nf][r];
          if (diag && scol > trow) w = 0.f;
          rs[r] += w;
          sP[(mf * 16 + q4 * 4 + r) * PS + nh * 32 + nf * 16 + r16] = (bf16_t)w;
        }
      }
      __syncthreads();
      // ---- PV
      bf16x8 pa[2][2];
#pragma unroll
      for (int i = 0; i < 2; ++i)
#pragma unroll
        for (int kt = 0; kt < 2; ++kt)
          pa[i][kt] = *(const bf16x8*)&sP[(i * 16 + r16) * PS + kt * 32 + q4 * 8];
#pragma unroll
      for (int nf = 0; nf < 4; ++nf) {
        const bf16_t* vpn = vp + (size_t)(nf * 16) * SEQ + s0;
#pragma unroll
        for (int kt = 0; kt < 2; ++kt) {
          bf16x8 vf = *(const bf16x8*)(vpn + kt * 32);
#pragma unroll
          for (int i = 0; i < 2; ++i)
            Of[i][nf] = __builtin_amdgcn_mfma_f32_16x16x32_bf16(pa[i][kt], vf, Of[i][nf], 0, 0, 0);
        }
      }
      __syncthreads();
    }
    // ---- n = max(|rowsum|, exp(-m))
#pragma unroll
    for (int r = 0; r < 4; ++r) {
#pragma unroll
      for (int off = 1; off < 16; off <<= 1) rs[r] += __shfl_xor(rs[r], off, 16);
    }
    if (r16 == 0) {
#pragma unroll
      for (int r = 0; r < 4; ++r) sRS[mf * 16 + q4 * 4 + r][nh] = rs[r];
    }
    __syncthreads();
    if (tid < 32) {
      float s = sRS[tid][0] + sRS[tid][1];
      sInvN[tid] = 1.0f / fmaxf(fabsf(s), __expf(-mb[bh_off + t0 + tid]));
    }
    __syncthreads();
    // ---- scale by 1/n, per-head RMSNorm partials
    float msq[2][4] = {{0.f, 0.f, 0.f, 0.f}, {0.f, 0.f, 0.f, 0.f}};
#pragma unroll
    for (int i = 0; i < 2; ++i) {
#pragma unroll
      for (int r = 0; r < 4; ++r) {
        float inv = sInvN[i * 16 + q4 * 4 + r];
#pragma unroll
        for (int nf = 0; nf < 4; ++nf) {
          float v = Of[i][nf][r] * inv;
          Of[i][nf][r] = v;
          msq[i][r] += v * v;
        }
      }
    }
#pragma unroll
    for (int i = 0; i < 2; ++i)
#pragma unroll
      for (int r = 0; r < 4; ++r) {
#pragma unroll
        for (int off = 1; off < 16; off <<= 1) msq[i][r] += __shfl_xor(msq[i][r], off, 16);
      }
    if (r16 == 0) {
#pragma unroll
      for (int i = 0; i < 2; ++i)
#pragma unroll
        for (int r = 0; r < 4; ++r) sMS[i * 16 + q4 * 4 + r][wv] = msq[i][r];
    }
    __syncthreads();
    if (tid < 32) {
      float s = sMS[tid][0] + sMS[tid][1] + sMS[tid][2] + sMS[tid][3];
      sSc[tid] = rsqrtf(s * (1.0f / DV) + 1e-6f);
    }
    __syncthreads();
    // ---- store with sigmoid(o_pre) gate and mh_w
#pragma unroll
    for (int i = 0; i < 2; ++i) {
#pragma unroll
      for (int r = 0; r < 4; ++r) {
        int trow = t0 + i * 16 + q4 * 4 + r;
        size_t gr = (size_t)(b * SEQ + trow);
        float scl = sSc[i * 16 + q4 * 4 + r];
#pragma unroll
        for (int nf = 0; nf < 4; ++nf) {
          int col = h * DV + dvb + nf * 16 + r16;
          float op = (float)qkvo[gr * QKVO_N + 4096 + col];
          float sig = 1.0f / (1.0f + __expf(-op));
          h_out[gr * D_MODEL + col] = (bf16_t)(Of[i][nf][r] * scl * mw[nf] * sig);
        }
      }
    }
  }
}

// ---------------------------------------------------------------- launcher

extern "C" void kernel_launch(void* const* d_in, const int* in_sizes, int n_in,
                              void* d_out, int out_size, void* d_ws, size_t ws_size,
                              hipStream_t stream) {
  const float* x      = (const float*)d_in[0];
  const float* n1w    = (const float*)d_in[1];
  const float* wq     = (const float*)d_in[2];
  const float* wk     = (const float*)d_in[3];
  const float* wvp    = (const float*)d_in[4];
  const float* w_ig   = (const float*)d_in[5];
  const float* b_ig   = (const float*)d_in[6];
  const float* w_fg   = (const float*)d_in[7];
  const float* b_fg   = (const float*)d_in[8];
  const float* w_og   = (const float*)d_in[9];
  const float* mh_w   = (const float*)d_in[10];
  const float* w_out  = (const float*)d_in[11];
  const float* n2w    = (const float*)d_in[12];
  const float* w_gate = (const float*)d_in[13];
  const float* w_up   = (const float*)d_in[14];
  const float* w_down = (const float*)d_in[15];
  float* out = (float*)d_out;
  (void)in_sizes; (void)n_in; (void)out_size; (void)ws_size;

  char* base = (char*)d_ws;
  size_t off = 0;
  auto alloc = [&](size_t bytes) -> void* {
    void* pp = base + off;
    off += (bytes + 255) & ~(size_t)255;
    return pp;
  };
  bf16_t* wT_qkvo = (bf16_t*)alloc((size_t)QKVO_N * 2048 * 2);
  bf16_t* wT_out  = (bf16_t*)alloc((size_t)2048 * 2048 * 2);
  bf16_t* wT_gate = (bf16_t*)alloc((size_t)FF * 2048 * 2);
  bf16_t* wT_up   = (bf16_t*)alloc((size_t)FF * 2048 * 2);
  bf16_t* wT_down = (bf16_t*)alloc((size_t)2048 * FF * 2);
  bf16_t* h_in    = (bf16_t*)alloc((size_t)MROWS * 2048 * 2);   // reused as h2; aliased by vtbuf
  float*  gate_pre= (float*)alloc((size_t)MROWS * 16 * 4);
  float*  ftb     = (float*)alloc((size_t)16 * SEQ * 4);
  float*  Gbuf    = (float*)alloc((size_t)16 * SEQ * 4);
  float*  mbuf    = (float*)alloc((size_t)16 * SEQ * 4);
  bf16_t* qkvo    = (bf16_t*)alloc((size_t)MROWS * QKVO_N * 2); // 48MB
  bf16_t* h_out   = (bf16_t*)alloc((size_t)MROWS * 2048 * 2);   // 16MB
  bf16_t* gbuf    = (bf16_t*)alloc((size_t)MROWS * FF * 2);
  bf16_t* tbuf    = qkvo;   // alias qkvo+h_out (both dead by MLP time)
  bf16_t* vtbuf   = h_in;   // alias: h_in dead after qkvo GEMM, reborn at rmsnorm2

  dim3 blk(256);
  // weight transposes -> bf16 [N][K]
  transpose_bf16_kernel<<<dim3(16, 32), blk, 0, stream>>>(wq, wT_qkvo, 2048, 1024);
  transpose_bf16_kernel<<<dim3(16, 32), blk, 0, stream>>>(wk, wT_qkvo + (size_t)1024 * 2048, 2048, 1024);
  transpose_bf16_kernel<<<dim3(32, 32), blk, 0, stream>>>(wvp, wT_qkvo + (size_t)2048 * 2048, 2048, 2048);
  transpose_bf16_kernel<<<dim3(32, 32), blk, 0, stream>>>(w_og, wT_qkvo + (size_t)4096 * 2048, 2048, 2048);
  transpose_bf16_kernel<<<dim3(32, 32), blk, 0, stream>>>(w_out, wT_out, 2048, 2048);
  transpose_bf16_kernel<<<dim3(128, 32), blk, 0, stream>>>(w_gate, wT_gate, 2048, FF);
  transpose_bf16_kernel<<<dim3(128, 32), blk, 0, stream>>>(w_up, wT_up, 2048, FF);
  transpose_bf16_kernel<<<dim3(32, 128), blk, 0, stream>>>(w_down, wT_down, FF, 2048);

  rmsnorm_kernel<true><<<MROWS, blk, 0, stream>>>(x, n1w, h_in, w_ig, b_ig, w_fg, b_fg, gate_pre);
  gate_scan_kernel<<<16, 64, 0, stream>>>(gate_pre, ftb, Gbuf, mbuf);

  gemm_kernel<0><<<dim3(QKVO_N / 128, 32), blk, 0, stream>>>(
      h_in, wT_qkvo, QKVO_N, 2048, nullptr, nullptr, qkvo, nullptr);

  vtrans_kernel<<<dim3(32, 4, 16), blk, 0, stream>>>(qkvo, vtbuf);
  attn_kernel<<<dim3(32, 16), blk, 0, stream>>>(qkvo, vtbuf, ftb, Gbuf, mbuf, mh_w, h_out);

  gemm_kernel<1><<<dim3(16, 32), blk, 0, stream>>>(
      h_out, wT_out, 2048, 2048, out, x, nullptr, nullptr);

  rmsnorm_kernel<false><<<MROWS, blk, 0, stream>>>(out, n2w, h_in,
      nullptr, nullptr, nullptr, nullptr, nullptr);

  gemm_kernel<0><<<dim3(FF / 128, 32), blk, 0, stream>>>(
      h_in, wT_gate, FF, 2048, nullptr, nullptr, gbuf, nullptr);
  gemm_kernel<2><<<dim3(FF / 128, 32), blk, 0, stream>>>(
      h_in, wT_up, FF, 2048, nullptr, nullptr, tbuf, gbuf);
  gemm_kernel<3><<<dim3(16, 32), blk, 0, stream>>>(
      tbuf, wT_down, 2048, FF, out, nullptr, nullptr, nullptr);
}